// Round 23
// baseline (513.126 us; speedup 1.0000x reference)
//
#include <hip/hip_runtime.h>
#include <hip/hip_bf16.h>
#include <stdint.h>

// GSC_kan: two grouped KAN convs (1x1, 3x3; G=8) + BatchNorm.
// Round 23: kan2 pinned at 29% occupancy; LDS 41472B is 512B over the
// 4-blocks/CU threshold (40960). Shrink slu to 16ch (32B/pos): base branch
// split into two K=16 halves (mfma 16x16x16), half-0 after chunk 3 (cc=4's
// top barrier orders reads before slu reuse), half-1 after the loop.
// LDS 31104B -> 4 blocks/CU. Everything else = R22 (148.7us).

#define NB 8
#define NF 9
#define CIN 128
#define COUT 256
#define GROUPS 8
#define HW 4096
#define BATCH 16

#define WFS_ELEMS 589824   // 256 * 32 * 8 * 9
#define WFB_ELEMS 73728    // 256 * 32 * 9
#define WF1S_ELEMS 32768
#define WF1B_ELEMS 8192

typedef __attribute__((ext_vector_type(8))) short bf16x8;
typedef __attribute__((ext_vector_type(4))) short bf16x4;
typedef __attribute__((ext_vector_type(4))) float f32x4;

__device__ __forceinline__ unsigned bf16r(float f) {
    union { float f; unsigned u; } c; c.f = f;
    unsigned r = c.u + 0x7FFF + ((c.u >> 16) & 1);   // RNE
    return r >> 16;
}
__device__ __forceinline__ unsigned bfpack2(float lo, float hi) {
    unsigned r;
    asm("v_cvt_pk_bf16_f32 %0, %1, %2" : "=v"(r) : "v"(lo), "v"(hi));
    return r;
}
// typed pack: two __float2bfloat16 (proven R18/R20) -> one u32 word
__device__ __forceinline__ unsigned bfpack2_typed(float lo, float hi) {
    __hip_bfloat16 a = __float2bfloat16(lo);
    __hip_bfloat16 b = __float2bfloat16(hi);
    unsigned short ua, ub;
    __builtin_memcpy(&ua, &a, 2);
    __builtin_memcpy(&ub, &b, 2);
    return (unsigned)ua | ((unsigned)ub << 16);
}

// K=16 bf16 MFMA (2-reg A/B)
__device__ __forceinline__ f32x4 mfma16(bf16x4 a, bf16x4 b, f32x4 c) {
#if __has_builtin(__builtin_amdgcn_mfma_f32_16x16x16bf16_1k)
    return __builtin_amdgcn_mfma_f32_16x16x16bf16_1k(a, b, c, 0, 0, 0);
#else
    asm("v_mfma_f32_16x16x16_bf16 %0, %1, %2, %0" : "+v"(c) : "v"(a), "v"(b));
    return c;
#endif
}

__device__ __forceinline__ float silu_fast(float v) {
    float e = __builtin_amdgcn_exp2f(v * -1.44269504088896f);
    return v * __builtin_amdgcn_rcpf(1.0f + e);
}

// uniform-knot cubic B-spline: 4 nonzero cardinal weights at interval k.
__device__ __forceinline__ void spline_w(float v, float& w0, float& w1,
                                         float& w2, float& w3, int& k) {
    float s = (v + 2.2f) * 2.5f;
    float fk = floorf(s);
    k = (int)fk;
    float u = s - fk;
    float um = 1.0f - u;
    float u2 = u * u, u3 = u2 * u;
    w0 = um * um * um * (1.0f / 6.0f);
    w1 = (3.0f * u3 - 6.0f * u2 + 4.0f) * (1.0f / 6.0f);
    w2 = (-3.0f * u3 + 3.0f * u2 + 3.0f * u + 1.0f) * (1.0f / 6.0f);
    w3 = u3 * (1.0f / 6.0f);
}

// ---- build the 8-bf16 spline row (zeros except w0..w3 at kk..kk+3) ----
__device__ __forceinline__ uint4 spline_row(float v, bool in, float& sv) {
    sv = silu_fast(v);
    float w0, w1, w2, w3; int k;
    spline_w(v, w0, w1, w2, w3, k);
    unsigned W0 = bfpack2(w0, w1);
    unsigned W1 = bfpack2(w2, w3);
    int kk = in ? (k - 3) : 99;                  // sentinel -> all-zero row
    unsigned odd = (unsigned)kk & 1u;
    unsigned A = W0 << 16;
    unsigned B = (W0 >> 16) | (W1 << 16);
    unsigned C = W1 >> 16;
    unsigned t0 = odd ? A : W0;
    unsigned t1 = odd ? B : W1;
    unsigned t2 = odd ? C : 0u;
    int q = kk >> 1;                             // floor((k-3)/2)
    uint4 pk;
    pk.x = (q == 0) ? t0 : (q == -1) ? t1 : (q == -2) ? t2 : 0u;
    pk.y = (q == 1) ? t0 : (q == 0)  ? t1 : (q == -1) ? t2 : 0u;
    pk.z = (q == 2) ? t0 : (q == 1)  ? t1 : (q == 0)  ? t2 : 0u;
    pk.w = (q == 3) ? t0 : (q == 2)  ? t1 : (q == 1)  ? t2 : 0u;
    return pk;
}

// expansion from raw bf16 bits (full-register int in)
__device__ __forceinline__ void expand_u(int raw, bool in,
                                         uint4& pk, unsigned& su) {
    float v = __uint_as_float(((unsigned)raw) << 16);
    float sv;
    pk = spline_row(v, in, sv);
    su = bf16r(sv);
}

// ---- repack: wfs (spline), wfb (base, K=16 halves), wf1s/wf1b (kan1) ----
__global__ void __launch_bounds__(256) repack2_kernel(
    const float* __restrict__ wb1, const float* __restrict__ ws1,
    const float* __restrict__ wb2, const float* __restrict__ ws2,
    unsigned short* __restrict__ wfs, unsigned short* __restrict__ wfb,
    unsigned short* __restrict__ wf1s, unsigned short* __restrict__ wf1b) {
    int i = blockIdx.x * 256 + threadIdx.x;
    if (i < WF1S_ELEMS) {   // [g][cc4][nf2][lane64][j8]
        int j = i & 7;
        int lane = (i >> 3) & 63;
        int nf = (i >> 9) & 1;
        int cc = (i >> 10) & 3;
        int g = i >> 12;
        int c_loc = cc * 4 + (lane >> 4);
        int cog = g * 32 + nf * 16 + (lane & 15);
        wf1s[i] = (unsigned short)bf16r(ws1[cog * 128 + c_loc * 8 + j]);
    }
    if (i < WF1B_ELEMS) {   // [g][nf2][lane64][j8], k=(lane>>4)*8+j, zero k>=16
        int j = i & 7;
        int lane = (i >> 3) & 63;
        int nf = (i >> 9) & 1;
        int g = (i >> 10) & 7;
        int k = (lane >> 4) * 8 + j;
        int cog = g * 32 + nf * 16 + (lane & 15);
        wf1b[i] = (k < 16) ? (unsigned short)bf16r(wb1[cog * 16 + k]) : 0;
    }
    if (i < WFB_ELEMS) {    // [g8][half2][dx3][dy3][nf2][lane64][j4], K=16
        int j = i & 3;
        int lane = (i >> 2) & 63;
        int nf = (i >> 8) & 1;
        int t = i >> 9;
        int dy = t % 3; t /= 3;
        int dx = t % 3; t /= 3;
        int half = t & 1; t >>= 1;
        int g = t;
        int ch = half * 16 + (lane >> 4) * 4 + j;   // k = (lane>>4)*4 + j
        int cog = g * 32 + nf * 16 + (lane & 15);
        wfb[i] = (unsigned short)bf16r(wb2[((cog * 32 + ch) * 3 + dy) * 3 + dx]);
    }
    if (i < WFS_ELEMS) {    // [g][cc8][dx3][dy3][nf2][lane64][j8]
        int j = i & 7;
        int t = i >> 3;
        int lane = t & 63; t >>= 6;
        int nf = t & 1; t >>= 1;
        int dy = t % 3; t /= 3;
        int dx = t % 3; t /= 3;
        int cc = t & 7; t >>= 3;
        int g = t;
        int c_loc = cc * 4 + (lane >> 4);
        int cog = g * 32 + nf * 16 + (lane & 15);
        float v = ws2[((cog * 256 + c_loc * 8 + j) * 3 + dy) * 3 + dx];
        wfs[i] = (unsigned short)bf16r(v);
    }
}

// ---- layer 1: 1x1 grouped KAN conv via bf16 MFMA; h1 out = bf16 ----
__global__ void __launch_bounds__(256, 4) kan1m_kernel(
    const float* __restrict__ x, const bf16x8* __restrict__ wf1s,
    const bf16x8* __restrict__ wf1b, const float* __restrict__ bb1,
    unsigned short* __restrict__ h1) {
    __shared__ __align__(16) unsigned char lds[32768];
    unsigned char* spl = lds;
    unsigned char* slu = lds + 16384;

    const int tid = threadIdx.x;
    const int lane = tid & 63;
    const int w = tid >> 6;
    const int blk = blockIdx.x;
    const int tile = blk & 15;
    const int g = (blk >> 4) & 7;
    const int b = blk >> 7;
    const int lrow = lane & 15;
    const int lhi = lane >> 4;
    const int posg0 = tile * 256;

    {
        int key = (tid >> 1) & 3;
        uint4 z = {0, 0, 0, 0};
        *reinterpret_cast<uint4*>(slu + tid * 64 + ((2 ^ key) << 4)) = z;
        *reinterpret_cast<uint4*>(slu + tid * 64 + ((3 ^ key) << 4)) = z;
    }

    const float* xg = x + ((size_t)b * CIN + g * 16) * HW + posg0;

    float xreg[4];
#pragma unroll
    for (int it = 0; it < 4; ++it) xreg[it] = xg[it * HW + tid];

    f32x4 acc[4][2];
#pragma unroll
    for (int m = 0; m < 4; ++m)
#pragma unroll
        for (int nf = 0; nf < 2; ++nf) {
            float bias = bb1[g * 32 + nf * 16 + lrow];
            acc[m][nf] = (f32x4){bias, bias, bias, bias};
        }

    for (int cc = 0; cc < 4; ++cc) {
        __syncthreads();
        int key = (tid >> 1) & 3;
#pragma unroll
        for (int it = 0; it < 4; ++it) {
            float sv;
            uint4 pk = spline_row(xreg[it], true, sv);
            *reinterpret_cast<uint4*>(spl + tid * 64 + ((it ^ key) << 4)) = pk;
            int cg = cc * 4 + it;
            *reinterpret_cast<unsigned short*>(
                slu + tid * 64 + (((cg >> 3) ^ key) << 4) + (cg & 7) * 2) =
                (unsigned short)bf16r(sv);
        }
        if (cc < 3) {
#pragma unroll
            for (int it = 0; it < 4; ++it)
                xreg[it] = xg[((cc + 1) * 4 + it) * HW + tid];
        }
        __syncthreads();
        const bf16x8* wpc = wf1s + (size_t)((g * 4 + cc) * 2) * 64;
        bf16x8 bf0 = wpc[lane];
        bf16x8 bf1 = wpc[64 + lane];
#pragma unroll
        for (int m = 0; m < 4; ++m) {
            int pos = w * 64 + m * 16 + lrow;
            int ra = pos * 64 + ((lhi ^ ((pos >> 1) & 3)) << 4);
            bf16x8 af = *reinterpret_cast<const bf16x8*>(spl + ra);
            acc[m][0] = __builtin_amdgcn_mfma_f32_16x16x32_bf16(af, bf0, acc[m][0], 0, 0, 0);
            acc[m][1] = __builtin_amdgcn_mfma_f32_16x16x32_bf16(af, bf1, acc[m][1], 0, 0, 0);
        }
    }
    {
        const bf16x8* wpb = wf1b + (size_t)(g * 2) * 64;
        bf16x8 bf0 = wpb[lane];
        bf16x8 bf1 = wpb[64 + lane];
#pragma unroll
        for (int m = 0; m < 4; ++m) {
            int pos = w * 64 + m * 16 + lrow;
            int ra = pos * 64 + ((lhi ^ ((pos >> 1) & 3)) << 4);
            bf16x8 af = *reinterpret_cast<const bf16x8*>(slu + ra);
            acc[m][0] = __builtin_amdgcn_mfma_f32_16x16x32_bf16(af, bf0, acc[m][0], 0, 0, 0);
            acc[m][1] = __builtin_amdgcn_mfma_f32_16x16x32_bf16(af, bf1, acc[m][1], 0, 0, 0);
        }
    }
    // typed bf16 epilogue, packed into one uint2 (8B) store per (m,nf)
#pragma unroll
    for (int m = 0; m < 4; ++m)
#pragma unroll
        for (int nf = 0; nf < 2; ++nf) {
            int co = g * 32 + nf * 16 + lrow;
            size_t base = ((size_t)b * COUT + co) * HW + posg0 + w * 64 + m * 16 + lhi * 4;
            uint2 o = {bfpack2_typed(acc[m][nf][0], acc[m][nf][1]),
                       bfpack2_typed(acc[m][nf][2], acc[m][nf][3])};
            *reinterpret_cast<uint2*>(&h1[base]) = o;
        }
}

// ---- MFMA (K=32) over one dx tap-column with precomputed LDS addrs ----
__device__ __forceinline__ void mfma_hr(
    const unsigned char* __restrict__ base, const int (&ra)[6],
    const bf16x8 (&bf)[3][2], f32x4 (&acc)[4][2]) {
#pragma unroll
    for (int hr = 0; hr < 6; ++hr) {
        bf16x8 af = *reinterpret_cast<const bf16x8*>(base + ra[hr]);
#pragma unroll
        for (int dy = 0; dy < 3; ++dy) {
            int y = hr - dy;
            if (y >= 0 && y < 4) {
                acc[y][0] = __builtin_amdgcn_mfma_f32_16x16x32_bf16(af, bf[dy][0], acc[y][0], 0, 0, 0);
                acc[y][1] = __builtin_amdgcn_mfma_f32_16x16x32_bf16(af, bf[dy][1], acc[y][1], 0, 0, 0);
            }
        }
    }
}

// ---- layer 2: 3x3 grouped KAN conv; slu = 16ch, base in two K=16 halves ----
__global__ void __launch_bounds__(256, 4) kan2_mfma6_kernel(
    const unsigned short* __restrict__ h1, const bf16x8* __restrict__ wfs,
    const bf16x4* __restrict__ wfb, const float* __restrict__ bb2,
    unsigned short* __restrict__ hb, float* __restrict__ partial2) {
    __shared__ __align__(16) unsigned char lds[31104];
    unsigned char* spl = lds;            // 20736 B: [p324][4ch x 16B]
    unsigned char* slu = lds + 20736;    // 10368 B: [p324][16ch x 2B]

    const int tid = threadIdx.x;
    const int lane = tid & 63;
    const int w = tid >> 6;
    const int blk = blockIdx.x;
    const int tile = blk & 15;
    const int g = (blk >> 4) & 7;
    const int b = blk >> 7;
    const int ty = (tile >> 2) * 16, tx = (tile & 3) * 16;
    const int lrow = lane & 15;
    const int lhi = lane >> 4;

    // staging descriptors (all cc-invariant)
    int offv[6], wadS[6], sluB[6], keysh3[6];
#pragma unroll
    for (int it = 0; it < 6; ++it) {
        int e = tid + it * 256;
        int ch = (e * 3237) >> 20;       // e/324 for e<1296
        int p = e - ch * 324;
        int hy = (p * 57) >> 10;         // p/18 for p<324
        int hx = p - hy * 18;
        int iy = ty + hy - 1, ix = tx + hx - 1;
        bool in = ((unsigned)iy < 64u) & ((unsigned)ix < 64u);
        offv[it] = in ? (ch * HW + iy * 64 + ix) : -1;
        int key = (p >> 1) & 3;
        wadS[it] = p * 64 + ((ch ^ key) << 4);
        sluB[it] = p * 32 + ch * 2;      // 32B rows; granule 8B = one chunk
        keysh3[it] = key << 3;
    }

    // A-frag LDS read addrs: spl (16B granules) and slu (8B granules)
    const int pbase0 = (w * 4) * 18 + lrow;
    int raA[3][6], raB[3][6];
#pragma unroll
    for (int dx = 0; dx < 3; ++dx)
#pragma unroll
        for (int hr = 0; hr < 6; ++hr) {
            int p = pbase0 + dx + hr * 18;
            int key = (p >> 1) & 3;
            raA[dx][hr] = p * 64 + ((lhi ^ key) << 4);
            raB[dx][hr] = p * 32 + ((lhi ^ key) << 3);
        }

    const unsigned short* h1g = h1 + (size_t)(b * COUT + g * 32) * HW;

    int vregU[6];
    uint4 ereg[6];
    unsigned sreg[6];
    // prologue: load+expand chunk 0; load chunk 1
#pragma unroll
    for (int it = 0; it < 6; ++it)
        if (it < 5 || tid < 16)
            vregU[it] = (offv[it] >= 0) ? (int)h1g[offv[it]] : 0;
#pragma unroll
    for (int it = 0; it < 6; ++it)
        if (it < 5 || tid < 16)
            expand_u(vregU[it], offv[it] >= 0, ereg[it], sreg[it]);
#pragma unroll
    for (int it = 0; it < 6; ++it)
        if (it < 5 || tid < 16)
            vregU[it] = (offv[it] >= 0) ? (int)h1g[4 * HW + offv[it]] : 0;

    f32x4 acc[4][2];
#pragma unroll
    for (int y = 0; y < 4; ++y)
#pragma unroll
        for (int nf = 0; nf < 2; ++nf) {
            float bias = bb2[g * 32 + nf * 16 + lrow];
            acc[y][nf] = (f32x4){bias, bias, bias, bias};
        }

    const bf16x8* wl = wfs + (size_t)(g * 8) * 18 * 64 + lane;

    for (int cc = 0; cc < 8; ++cc) {
        // dx=0 B-frags issued before stage (in flight across barrier)
        bf16x8 bf0[3][2];
#pragma unroll
        for (int dy = 0; dy < 3; ++dy)
#pragma unroll
            for (int nf = 0; nf < 2; ++nf)
                bf0[dy][nf] = wl[(dy * 2 + nf) * 64];

        __syncthreads();                 // spl free; slu half reads done
        {
            int t8 = (cc & 3) << 3;      // slu granule = chunk-within-half
#pragma unroll
            for (int it = 0; it < 6; ++it)
                if (it < 5 || tid < 16) {
                    *reinterpret_cast<uint4*>(spl + wadS[it]) = ereg[it];
                    *reinterpret_cast<unsigned short*>(
                        slu + sluB[it] + (t8 ^ keysh3[it])) =
                        (unsigned short)sreg[it];
                }
        }
        __syncthreads();                 // staging complete

        bf16x8 bf1[3][2], bf2[3][2];
#pragma unroll
        for (int dy = 0; dy < 3; ++dy)
#pragma unroll
            for (int nf = 0; nf < 2; ++nf)
                bf1[dy][nf] = wl[(6 + dy * 2 + nf) * 64];
        __builtin_amdgcn_s_setprio(1);
        mfma_hr(spl, raA[0], bf0, acc);
        __builtin_amdgcn_s_setprio(0);
#pragma unroll
        for (int dy = 0; dy < 3; ++dy)
#pragma unroll
            for (int nf = 0; nf < 2; ++nf)
                bf2[dy][nf] = wl[(12 + dy * 2 + nf) * 64];
        __builtin_amdgcn_s_setprio(1);
        mfma_hr(spl, raA[1], bf1, acc);
        __builtin_amdgcn_s_setprio(0);
        // expansion for cc+1 + loads for cc+2 (overlap MFMA pipe)
        if (cc < 7) {
#pragma unroll
            for (int it = 0; it < 6; ++it)
                if (it < 5 || tid < 16)
                    expand_u(vregU[it], offv[it] >= 0, ereg[it], sreg[it]);
        }
        if (cc < 6) {
#pragma unroll
            for (int it = 0; it < 6; ++it)
                if (it < 5 || tid < 16)
                    vregU[it] = (offv[it] >= 0)
                        ? (int)h1g[(size_t)((cc + 2) * 4) * HW + offv[it]] : 0;
        }
        __builtin_amdgcn_s_setprio(1);
        mfma_hr(spl, raA[2], bf2, acc);
        __builtin_amdgcn_s_setprio(0);
        // base half 0 (ch 0-15) after chunk 3; cc=4's top barrier orders
        // these slu reads before the half-1 staging overwrites.
        if (cc == 3) {
#pragma unroll
            for (int dx = 0; dx < 3; ++dx) {
                bf16x4 bf[3][2];
#pragma unroll
                for (int dy = 0; dy < 3; ++dy)
#pragma unroll
                    for (int nf = 0; nf < 2; ++nf)
                        bf[dy][nf] = wfb[((((g * 2 + 0) * 3 + dx) * 3 + dy) * 2 + nf) * 64 + lane];
                __builtin_amdgcn_s_setprio(1);
#pragma unroll
                for (int hr = 0; hr < 6; ++hr) {
                    bf16x4 af = *reinterpret_cast<const bf16x4*>(slu + raB[dx][hr]);
#pragma unroll
                    for (int dy = 0; dy < 3; ++dy) {
                        int y = hr - dy;
                        if (y >= 0 && y < 4) {
                            acc[y][0] = mfma16(af, bf[dy][0], acc[y][0]);
                            acc[y][1] = mfma16(af, bf[dy][1], acc[y][1]);
                        }
                    }
                }
                __builtin_amdgcn_s_setprio(0);
            }
        }
        wl += 18 * 64;
    }

    // base half 1 (ch 16-31): slu written during cc=4..7, all visible
    {
#pragma unroll
        for (int dx = 0; dx < 3; ++dx) {
            bf16x4 bf[3][2];
#pragma unroll
            for (int dy = 0; dy < 3; ++dy)
#pragma unroll
                for (int nf = 0; nf < 2; ++nf)
                    bf[dy][nf] = wfb[((((g * 2 + 1) * 3 + dx) * 3 + dy) * 2 + nf) * 64 + lane];
            __builtin_amdgcn_s_setprio(1);
#pragma unroll
            for (int hr = 0; hr < 6; ++hr) {
                bf16x4 af = *reinterpret_cast<const bf16x4*>(slu + raB[dx][hr]);
#pragma unroll
                for (int dy = 0; dy < 3; ++dy) {
                    int y = hr - dy;
                    if (y >= 0 && y < 4) {
                        acc[y][0] = mfma16(af, bf[dy][0], acc[y][0]);
                        acc[y][1] = mfma16(af, bf[dy][1], acc[y][1]);
                    }
                }
            }
            __builtin_amdgcn_s_setprio(0);
        }
    }

    // write hb (bf16): row (m) = x = lhi*4 + reg, col (n) = co = lrow
#pragma unroll
    for (int y = 0; y < 4; ++y) {
        int oy = ty + w * 4 + y;
#pragma unroll
        for (int nf = 0; nf < 2; ++nf) {
            int co = g * 32 + nf * 16 + lrow;
            uint2 o = {bfpack2_typed(acc[y][nf][0], acc[y][nf][1]),
                       bfpack2_typed(acc[y][nf][2], acc[y][nf][3])};
            *reinterpret_cast<uint2*>(
                &hb[(((size_t)b * COUT + co) * 64 + oy) * 64 + tx + lhi * 4]) = o;
        }
    }

    // fused BN partial sums (deterministic; pre-rounding accs)
    float s0 = 0.0f, q0 = 0.0f, s1 = 0.0f, q1 = 0.0f;
#pragma unroll
    for (int y = 0; y < 4; ++y)
#pragma unroll
        for (int i = 0; i < 4; ++i) {
            float a0 = acc[y][0][i], a1 = acc[y][1][i];
            s0 += a0; q0 = fmaf(a0, a0, q0);
            s1 += a1; q1 = fmaf(a1, a1, q1);
        }
    s0 += __shfl_xor(s0, 16); s0 += __shfl_xor(s0, 32);
    q0 += __shfl_xor(q0, 16); q0 += __shfl_xor(q0, 32);
    s1 += __shfl_xor(s1, 16); s1 += __shfl_xor(s1, 32);
    q1 += __shfl_xor(q1, 16); q1 += __shfl_xor(q1, 32);
    __syncthreads();
    float* stb = reinterpret_cast<float*>(lds);
    if (lane < 16) {
        int base = (w * 16 + lane) * 4;
        stb[base] = s0; stb[base + 1] = q0;
        stb[base + 2] = s1; stb[base + 3] = q1;
    }
    __syncthreads();
    if (tid < 64) {
        int slot = tid >> 1;
        int j = tid & 1;
        int lr = slot & 15, nf = slot >> 4;
        float a = 0.0f;
#pragma unroll
        for (int wv = 0; wv < 4; ++wv)
            a += stb[(wv * 16 + lr) * 4 + nf * 2 + j];
        partial2[blk * 64 + tid] = a;
    }
}

// ---- BN stats: one block per channel, reduce 256 block-partials ----
__global__ void __launch_bounds__(256) bnstat2_kernel(
    const float* __restrict__ partial2, const float* __restrict__ gamma,
    const float* __restrict__ beta, float* __restrict__ stats) {
    int co = blockIdx.x;
    int t = threadIdx.x;
    int g = co >> 5, loc = co & 31;
    int b = t >> 4, tile = t & 15;
    int blk = (b * 8 + g) * 16 + tile;
    float s = partial2[blk * 64 + loc * 2];
    float ss = partial2[blk * 64 + loc * 2 + 1];
    __shared__ float r1[256], r2[256];
    r1[t] = s; r2[t] = ss;
    __syncthreads();
    for (int o = 128; o > 0; o >>= 1) {
        if (t < o) { r1[t] += r1[t + o]; r2[t] += r2[t + o]; }
        __syncthreads();
    }
    if (t == 0) {
        const float invn = 1.0f / 65536.0f;
        float mean = r1[0] * invn;
        float var = r2[0] * invn - mean * mean;
        float sc = gamma[co] * rsqrtf(var + 1e-5f);
        stats[2 * co] = sc;
        stats[2 * co + 1] = beta[co] - mean * sc;
    }
}

// ---- BN apply: read hb (bf16, uint4 of 8), write d_out (fp32) ----
__global__ void __launch_bounds__(256) bnapply_kernel(
    const unsigned short* __restrict__ hb, const float* __restrict__ stats,
    float* __restrict__ out) {
    int i = blockIdx.x * 256 + threadIdx.x;   // 2,097,152 threads x 8 elems
    int co = (i >> 9) & 255;                  // 512 groups per (b,co) plane
    float sc = stats[2 * co], sh = stats[2 * co + 1];
    uint4 v = *reinterpret_cast<const uint4*>(hb + (size_t)i * 8);
    float4 o0, o1;
    o0.x = fmaf(__uint_as_float(v.x << 16), sc, sh);
    o0.y = fmaf(__uint_as_float(v.x & 0xFFFF0000u), sc, sh);
    o0.z = fmaf(__uint_as_float(v.y << 16), sc, sh);
    o0.w = fmaf(__uint_as_float(v.y & 0xFFFF0000u), sc, sh);
    o1.x = fmaf(__uint_as_float(v.z << 16), sc, sh);
    o1.y = fmaf(__uint_as_float(v.z & 0xFFFF0000u), sc, sh);
    o1.z = fmaf(__uint_as_float(v.w << 16), sc, sh);
    o1.w = fmaf(__uint_as_float(v.w & 0xFFFF0000u), sc, sh);
    float4* op = reinterpret_cast<float4*>(out + (size_t)i * 8);
    op[0] = o0;
    op[1] = o1;
}

extern "C" void kernel_launch(void* const* d_in, const int* in_sizes, int n_in,
                              void* d_out, int out_size, void* d_ws, size_t ws_size,
                              hipStream_t stream) {
    const float* x   = (const float*)d_in[0];
    const float* wb1 = (const float*)d_in[1];
    const float* bb1 = (const float*)d_in[2];
    const float* ws1 = (const float*)d_in[3];
    const float* wb2 = (const float*)d_in[4];
    const float* bb2 = (const float*)d_in[5];
    const float* ws2 = (const float*)d_in[6];
    const float* gamma = (const float*)d_in[7];
    const float* beta  = (const float*)d_in[8];

    char* ws = (char*)d_ws;
    unsigned short* wfs  = (unsigned short*)ws;              // 1,179,648 B
    unsigned short* wfb  = (unsigned short*)(ws + 1179648);  // 147,456 B
    unsigned short* wf1s = (unsigned short*)(ws + 1327104);  // 65,536 B
    unsigned short* wf1b = (unsigned short*)(ws + 1392640);  // 16,384 B
    float* partial2 = (float*)(ws + 1409024);                // 524,288 B
    float* stats    = (float*)(ws + 1933312);                // 2,048 B
    unsigned short* h1 = (unsigned short*)(ws + 1935360);    // 33,554,432 B
    unsigned short* hb = (unsigned short*)(ws + 35489792);   // 33,554,432 B

    repack2_kernel<<<(WFS_ELEMS + 255) / 256, 256, 0, stream>>>(
        wb1, ws1, wb2, ws2, wfs, wfb, wf1s, wf1b);
    kan1m_kernel<<<BATCH * GROUPS * 16, 256, 0, stream>>>(
        x, (const bf16x8*)wf1s, (const bf16x8*)wf1b, bb1, h1);
    kan2_mfma6_kernel<<<BATCH * GROUPS * 16, 256, 0, stream>>>(
        h1, (const bf16x8*)wfs, (const bf16x4*)wfb, bb2, hb, partial2);
    bnstat2_kernel<<<COUT, 256, 0, stream>>>(partial2, gamma, beta, stats);
    bnapply_kernel<<<8192, 256, 0, stream>>>(hb, stats, (float*)d_out);
}

// Round 24
// 309.038 us; speedup vs baseline: 1.6604x; 1.6604x over previous
//
#include <hip/hip_runtime.h>
#include <hip/hip_bf16.h>
#include <stdint.h>

// GSC_kan: two grouped KAN convs (1x1, 3x3; G=8) + BatchNorm.
// Round 24: R23's slu-halving was CORRECT but __launch_bounds__(256,4)
// capped VGPR at 64 -> ~20-reg spill -> 830MB scratch FETCH -> 500us.
// Fix: (256,3) restores the proven 84+ VGPR budget; hardware still fits
// 4 blocks/CU (LDS 31104B, VGPR<=128). Everything else = R23.

#define NB 8
#define NF 9
#define CIN 128
#define COUT 256
#define GROUPS 8
#define HW 4096
#define BATCH 16

#define WFS_ELEMS 589824   // 256 * 32 * 8 * 9
#define WFB_ELEMS 73728    // 256 * 32 * 9
#define WF1S_ELEMS 32768
#define WF1B_ELEMS 8192

typedef __attribute__((ext_vector_type(8))) short bf16x8;
typedef __attribute__((ext_vector_type(4))) short bf16x4;
typedef __attribute__((ext_vector_type(4))) float f32x4;

__device__ __forceinline__ unsigned bf16r(float f) {
    union { float f; unsigned u; } c; c.f = f;
    unsigned r = c.u + 0x7FFF + ((c.u >> 16) & 1);   // RNE
    return r >> 16;
}
__device__ __forceinline__ unsigned bfpack2(float lo, float hi) {
    unsigned r;
    asm("v_cvt_pk_bf16_f32 %0, %1, %2" : "=v"(r) : "v"(lo), "v"(hi));
    return r;
}
// typed pack: two __float2bfloat16 (proven R18/R20) -> one u32 word
__device__ __forceinline__ unsigned bfpack2_typed(float lo, float hi) {
    __hip_bfloat16 a = __float2bfloat16(lo);
    __hip_bfloat16 b = __float2bfloat16(hi);
    unsigned short ua, ub;
    __builtin_memcpy(&ua, &a, 2);
    __builtin_memcpy(&ub, &b, 2);
    return (unsigned)ua | ((unsigned)ub << 16);
}

// K=16 bf16 MFMA (2-reg A/B)
__device__ __forceinline__ f32x4 mfma16(bf16x4 a, bf16x4 b, f32x4 c) {
#if __has_builtin(__builtin_amdgcn_mfma_f32_16x16x16bf16_1k)
    return __builtin_amdgcn_mfma_f32_16x16x16bf16_1k(a, b, c, 0, 0, 0);
#else
    asm("v_mfma_f32_16x16x16_bf16 %0, %1, %2, %0" : "+v"(c) : "v"(a), "v"(b));
    return c;
#endif
}

__device__ __forceinline__ float silu_fast(float v) {
    float e = __builtin_amdgcn_exp2f(v * -1.44269504088896f);
    return v * __builtin_amdgcn_rcpf(1.0f + e);
}

// uniform-knot cubic B-spline: 4 nonzero cardinal weights at interval k.
__device__ __forceinline__ void spline_w(float v, float& w0, float& w1,
                                         float& w2, float& w3, int& k) {
    float s = (v + 2.2f) * 2.5f;
    float fk = floorf(s);
    k = (int)fk;
    float u = s - fk;
    float um = 1.0f - u;
    float u2 = u * u, u3 = u2 * u;
    w0 = um * um * um * (1.0f / 6.0f);
    w1 = (3.0f * u3 - 6.0f * u2 + 4.0f) * (1.0f / 6.0f);
    w2 = (-3.0f * u3 + 3.0f * u2 + 3.0f * u + 1.0f) * (1.0f / 6.0f);
    w3 = u3 * (1.0f / 6.0f);
}

// ---- build the 8-bf16 spline row (zeros except w0..w3 at kk..kk+3) ----
__device__ __forceinline__ uint4 spline_row(float v, bool in, float& sv) {
    sv = silu_fast(v);
    float w0, w1, w2, w3; int k;
    spline_w(v, w0, w1, w2, w3, k);
    unsigned W0 = bfpack2(w0, w1);
    unsigned W1 = bfpack2(w2, w3);
    int kk = in ? (k - 3) : 99;                  // sentinel -> all-zero row
    unsigned odd = (unsigned)kk & 1u;
    unsigned A = W0 << 16;
    unsigned B = (W0 >> 16) | (W1 << 16);
    unsigned C = W1 >> 16;
    unsigned t0 = odd ? A : W0;
    unsigned t1 = odd ? B : W1;
    unsigned t2 = odd ? C : 0u;
    int q = kk >> 1;                             // floor((k-3)/2)
    uint4 pk;
    pk.x = (q == 0) ? t0 : (q == -1) ? t1 : (q == -2) ? t2 : 0u;
    pk.y = (q == 1) ? t0 : (q == 0)  ? t1 : (q == -1) ? t2 : 0u;
    pk.z = (q == 2) ? t0 : (q == 1)  ? t1 : (q == 0)  ? t2 : 0u;
    pk.w = (q == 3) ? t0 : (q == 2)  ? t1 : (q == 1)  ? t2 : 0u;
    return pk;
}

// expansion from raw bf16 bits (full-register int in)
__device__ __forceinline__ void expand_u(int raw, bool in,
                                         uint4& pk, unsigned& su) {
    float v = __uint_as_float(((unsigned)raw) << 16);
    float sv;
    pk = spline_row(v, in, sv);
    su = bf16r(sv);
}

// ---- repack: wfs (spline), wfb (base, K=16 halves), wf1s/wf1b (kan1) ----
__global__ void __launch_bounds__(256) repack2_kernel(
    const float* __restrict__ wb1, const float* __restrict__ ws1,
    const float* __restrict__ wb2, const float* __restrict__ ws2,
    unsigned short* __restrict__ wfs, unsigned short* __restrict__ wfb,
    unsigned short* __restrict__ wf1s, unsigned short* __restrict__ wf1b) {
    int i = blockIdx.x * 256 + threadIdx.x;
    if (i < WF1S_ELEMS) {   // [g][cc4][nf2][lane64][j8]
        int j = i & 7;
        int lane = (i >> 3) & 63;
        int nf = (i >> 9) & 1;
        int cc = (i >> 10) & 3;
        int g = i >> 12;
        int c_loc = cc * 4 + (lane >> 4);
        int cog = g * 32 + nf * 16 + (lane & 15);
        wf1s[i] = (unsigned short)bf16r(ws1[cog * 128 + c_loc * 8 + j]);
    }
    if (i < WF1B_ELEMS) {   // [g][nf2][lane64][j8], k=(lane>>4)*8+j, zero k>=16
        int j = i & 7;
        int lane = (i >> 3) & 63;
        int nf = (i >> 9) & 1;
        int g = (i >> 10) & 7;
        int k = (lane >> 4) * 8 + j;
        int cog = g * 32 + nf * 16 + (lane & 15);
        wf1b[i] = (k < 16) ? (unsigned short)bf16r(wb1[cog * 16 + k]) : 0;
    }
    if (i < WFB_ELEMS) {    // [g8][half2][dx3][dy3][nf2][lane64][j4], K=16
        int j = i & 3;
        int lane = (i >> 2) & 63;
        int nf = (i >> 8) & 1;
        int t = i >> 9;
        int dy = t % 3; t /= 3;
        int dx = t % 3; t /= 3;
        int half = t & 1; t >>= 1;
        int g = t;
        int ch = half * 16 + (lane >> 4) * 4 + j;   // k = (lane>>4)*4 + j
        int cog = g * 32 + nf * 16 + (lane & 15);
        wfb[i] = (unsigned short)bf16r(wb2[((cog * 32 + ch) * 3 + dy) * 3 + dx]);
    }
    if (i < WFS_ELEMS) {    // [g][cc8][dx3][dy3][nf2][lane64][j8]
        int j = i & 7;
        int t = i >> 3;
        int lane = t & 63; t >>= 6;
        int nf = t & 1; t >>= 1;
        int dy = t % 3; t /= 3;
        int dx = t % 3; t /= 3;
        int cc = t & 7; t >>= 3;
        int g = t;
        int c_loc = cc * 4 + (lane >> 4);
        int cog = g * 32 + nf * 16 + (lane & 15);
        float v = ws2[((cog * 256 + c_loc * 8 + j) * 3 + dy) * 3 + dx];
        wfs[i] = (unsigned short)bf16r(v);
    }
}

// ---- layer 1: 1x1 grouped KAN conv via bf16 MFMA; h1 out = bf16 ----
__global__ void __launch_bounds__(256, 4) kan1m_kernel(
    const float* __restrict__ x, const bf16x8* __restrict__ wf1s,
    const bf16x8* __restrict__ wf1b, const float* __restrict__ bb1,
    unsigned short* __restrict__ h1) {
    __shared__ __align__(16) unsigned char lds[32768];
    unsigned char* spl = lds;
    unsigned char* slu = lds + 16384;

    const int tid = threadIdx.x;
    const int lane = tid & 63;
    const int w = tid >> 6;
    const int blk = blockIdx.x;
    const int tile = blk & 15;
    const int g = (blk >> 4) & 7;
    const int b = blk >> 7;
    const int lrow = lane & 15;
    const int lhi = lane >> 4;
    const int posg0 = tile * 256;

    {
        int key = (tid >> 1) & 3;
        uint4 z = {0, 0, 0, 0};
        *reinterpret_cast<uint4*>(slu + tid * 64 + ((2 ^ key) << 4)) = z;
        *reinterpret_cast<uint4*>(slu + tid * 64 + ((3 ^ key) << 4)) = z;
    }

    const float* xg = x + ((size_t)b * CIN + g * 16) * HW + posg0;

    float xreg[4];
#pragma unroll
    for (int it = 0; it < 4; ++it) xreg[it] = xg[it * HW + tid];

    f32x4 acc[4][2];
#pragma unroll
    for (int m = 0; m < 4; ++m)
#pragma unroll
        for (int nf = 0; nf < 2; ++nf) {
            float bias = bb1[g * 32 + nf * 16 + lrow];
            acc[m][nf] = (f32x4){bias, bias, bias, bias};
        }

    for (int cc = 0; cc < 4; ++cc) {
        __syncthreads();
        int key = (tid >> 1) & 3;
#pragma unroll
        for (int it = 0; it < 4; ++it) {
            float sv;
            uint4 pk = spline_row(xreg[it], true, sv);
            *reinterpret_cast<uint4*>(spl + tid * 64 + ((it ^ key) << 4)) = pk;
            int cg = cc * 4 + it;
            *reinterpret_cast<unsigned short*>(
                slu + tid * 64 + (((cg >> 3) ^ key) << 4) + (cg & 7) * 2) =
                (unsigned short)bf16r(sv);
        }
        if (cc < 3) {
#pragma unroll
            for (int it = 0; it < 4; ++it)
                xreg[it] = xg[((cc + 1) * 4 + it) * HW + tid];
        }
        __syncthreads();
        const bf16x8* wpc = wf1s + (size_t)((g * 4 + cc) * 2) * 64;
        bf16x8 bf0 = wpc[lane];
        bf16x8 bf1 = wpc[64 + lane];
#pragma unroll
        for (int m = 0; m < 4; ++m) {
            int pos = w * 64 + m * 16 + lrow;
            int ra = pos * 64 + ((lhi ^ ((pos >> 1) & 3)) << 4);
            bf16x8 af = *reinterpret_cast<const bf16x8*>(spl + ra);
            acc[m][0] = __builtin_amdgcn_mfma_f32_16x16x32_bf16(af, bf0, acc[m][0], 0, 0, 0);
            acc[m][1] = __builtin_amdgcn_mfma_f32_16x16x32_bf16(af, bf1, acc[m][1], 0, 0, 0);
        }
    }
    {
        const bf16x8* wpb = wf1b + (size_t)(g * 2) * 64;
        bf16x8 bf0 = wpb[lane];
        bf16x8 bf1 = wpb[64 + lane];
#pragma unroll
        for (int m = 0; m < 4; ++m) {
            int pos = w * 64 + m * 16 + lrow;
            int ra = pos * 64 + ((lhi ^ ((pos >> 1) & 3)) << 4);
            bf16x8 af = *reinterpret_cast<const bf16x8*>(slu + ra);
            acc[m][0] = __builtin_amdgcn_mfma_f32_16x16x32_bf16(af, bf0, acc[m][0], 0, 0, 0);
            acc[m][1] = __builtin_amdgcn_mfma_f32_16x16x32_bf16(af, bf1, acc[m][1], 0, 0, 0);
        }
    }
    // typed bf16 epilogue, packed into one uint2 (8B) store per (m,nf)
#pragma unroll
    for (int m = 0; m < 4; ++m)
#pragma unroll
        for (int nf = 0; nf < 2; ++nf) {
            int co = g * 32 + nf * 16 + lrow;
            size_t base = ((size_t)b * COUT + co) * HW + posg0 + w * 64 + m * 16 + lhi * 4;
            uint2 o = {bfpack2_typed(acc[m][nf][0], acc[m][nf][1]),
                       bfpack2_typed(acc[m][nf][2], acc[m][nf][3])};
            *reinterpret_cast<uint2*>(&h1[base]) = o;
        }
}

// ---- MFMA (K=32) over one dx tap-column with precomputed LDS addrs ----
__device__ __forceinline__ void mfma_hr(
    const unsigned char* __restrict__ base, const int (&ra)[6],
    const bf16x8 (&bf)[3][2], f32x4 (&acc)[4][2]) {
#pragma unroll
    for (int hr = 0; hr < 6; ++hr) {
        bf16x8 af = *reinterpret_cast<const bf16x8*>(base + ra[hr]);
#pragma unroll
        for (int dy = 0; dy < 3; ++dy) {
            int y = hr - dy;
            if (y >= 0 && y < 4) {
                acc[y][0] = __builtin_amdgcn_mfma_f32_16x16x32_bf16(af, bf[dy][0], acc[y][0], 0, 0, 0);
                acc[y][1] = __builtin_amdgcn_mfma_f32_16x16x32_bf16(af, bf[dy][1], acc[y][1], 0, 0, 0);
            }
        }
    }
}

// ---- layer 2: 3x3 grouped KAN conv; slu = 16ch, base in two K=16 halves ----
__global__ void __launch_bounds__(256, 3) kan2_mfma6_kernel(
    const unsigned short* __restrict__ h1, const bf16x8* __restrict__ wfs,
    const bf16x4* __restrict__ wfb, const float* __restrict__ bb2,
    unsigned short* __restrict__ hb, float* __restrict__ partial2) {
    __shared__ __align__(16) unsigned char lds[31104];
    unsigned char* spl = lds;            // 20736 B: [p324][4ch x 16B]
    unsigned char* slu = lds + 20736;    // 10368 B: [p324][16ch x 2B]

    const int tid = threadIdx.x;
    const int lane = tid & 63;
    const int w = tid >> 6;
    const int blk = blockIdx.x;
    const int tile = blk & 15;
    const int g = (blk >> 4) & 7;
    const int b = blk >> 7;
    const int ty = (tile >> 2) * 16, tx = (tile & 3) * 16;
    const int lrow = lane & 15;
    const int lhi = lane >> 4;

    // staging descriptors (all cc-invariant)
    int offv[6], wadS[6], sluB[6], keysh3[6];
#pragma unroll
    for (int it = 0; it < 6; ++it) {
        int e = tid + it * 256;
        int ch = (e * 3237) >> 20;       // e/324 for e<1296
        int p = e - ch * 324;
        int hy = (p * 57) >> 10;         // p/18 for p<324
        int hx = p - hy * 18;
        int iy = ty + hy - 1, ix = tx + hx - 1;
        bool in = ((unsigned)iy < 64u) & ((unsigned)ix < 64u);
        offv[it] = in ? (ch * HW + iy * 64 + ix) : -1;
        int key = (p >> 1) & 3;
        wadS[it] = p * 64 + ((ch ^ key) << 4);
        sluB[it] = p * 32 + ch * 2;      // 32B rows; granule 8B = one chunk
        keysh3[it] = key << 3;
    }

    // A-frag LDS read addrs: spl (16B granules) and slu (8B granules)
    const int pbase0 = (w * 4) * 18 + lrow;
    int raA[3][6], raB[3][6];
#pragma unroll
    for (int dx = 0; dx < 3; ++dx)
#pragma unroll
        for (int hr = 0; hr < 6; ++hr) {
            int p = pbase0 + dx + hr * 18;
            int key = (p >> 1) & 3;
            raA[dx][hr] = p * 64 + ((lhi ^ key) << 4);
            raB[dx][hr] = p * 32 + ((lhi ^ key) << 3);
        }

    const unsigned short* h1g = h1 + (size_t)(b * COUT + g * 32) * HW;

    int vregU[6];
    uint4 ereg[6];
    unsigned sreg[6];
    // prologue: load+expand chunk 0; load chunk 1
#pragma unroll
    for (int it = 0; it < 6; ++it)
        if (it < 5 || tid < 16)
            vregU[it] = (offv[it] >= 0) ? (int)h1g[offv[it]] : 0;
#pragma unroll
    for (int it = 0; it < 6; ++it)
        if (it < 5 || tid < 16)
            expand_u(vregU[it], offv[it] >= 0, ereg[it], sreg[it]);
#pragma unroll
    for (int it = 0; it < 6; ++it)
        if (it < 5 || tid < 16)
            vregU[it] = (offv[it] >= 0) ? (int)h1g[4 * HW + offv[it]] : 0;

    f32x4 acc[4][2];
#pragma unroll
    for (int y = 0; y < 4; ++y)
#pragma unroll
        for (int nf = 0; nf < 2; ++nf) {
            float bias = bb2[g * 32 + nf * 16 + lrow];
            acc[y][nf] = (f32x4){bias, bias, bias, bias};
        }

    const bf16x8* wl = wfs + (size_t)(g * 8) * 18 * 64 + lane;

    for (int cc = 0; cc < 8; ++cc) {
        // dx=0 B-frags issued before stage (in flight across barrier)
        bf16x8 bf0[3][2];
#pragma unroll
        for (int dy = 0; dy < 3; ++dy)
#pragma unroll
            for (int nf = 0; nf < 2; ++nf)
                bf0[dy][nf] = wl[(dy * 2 + nf) * 64];

        __syncthreads();                 // spl free; slu half reads done
        {
            int t8 = (cc & 3) << 3;      // slu granule = chunk-within-half
#pragma unroll
            for (int it = 0; it < 6; ++it)
                if (it < 5 || tid < 16) {
                    *reinterpret_cast<uint4*>(spl + wadS[it]) = ereg[it];
                    *reinterpret_cast<unsigned short*>(
                        slu + sluB[it] + (t8 ^ keysh3[it])) =
                        (unsigned short)sreg[it];
                }
        }
        __syncthreads();                 // staging complete

        bf16x8 bf1[3][2], bf2[3][2];
#pragma unroll
        for (int dy = 0; dy < 3; ++dy)
#pragma unroll
            for (int nf = 0; nf < 2; ++nf)
                bf1[dy][nf] = wl[(6 + dy * 2 + nf) * 64];
        __builtin_amdgcn_s_setprio(1);
        mfma_hr(spl, raA[0], bf0, acc);
        __builtin_amdgcn_s_setprio(0);
#pragma unroll
        for (int dy = 0; dy < 3; ++dy)
#pragma unroll
            for (int nf = 0; nf < 2; ++nf)
                bf2[dy][nf] = wl[(12 + dy * 2 + nf) * 64];
        __builtin_amdgcn_s_setprio(1);
        mfma_hr(spl, raA[1], bf1, acc);
        __builtin_amdgcn_s_setprio(0);
        // expansion for cc+1 + loads for cc+2 (overlap MFMA pipe)
        if (cc < 7) {
#pragma unroll
            for (int it = 0; it < 6; ++it)
                if (it < 5 || tid < 16)
                    expand_u(vregU[it], offv[it] >= 0, ereg[it], sreg[it]);
        }
        if (cc < 6) {
#pragma unroll
            for (int it = 0; it < 6; ++it)
                if (it < 5 || tid < 16)
                    vregU[it] = (offv[it] >= 0)
                        ? (int)h1g[(size_t)((cc + 2) * 4) * HW + offv[it]] : 0;
        }
        __builtin_amdgcn_s_setprio(1);
        mfma_hr(spl, raA[2], bf2, acc);
        __builtin_amdgcn_s_setprio(0);
        // base half 0 (ch 0-15) after chunk 3; cc=4's top barrier orders
        // these slu reads before the half-1 staging overwrites.
        if (cc == 3) {
#pragma unroll
            for (int dx = 0; dx < 3; ++dx) {
                bf16x4 bf[3][2];
#pragma unroll
                for (int dy = 0; dy < 3; ++dy)
#pragma unroll
                    for (int nf = 0; nf < 2; ++nf)
                        bf[dy][nf] = wfb[((((g * 2 + 0) * 3 + dx) * 3 + dy) * 2 + nf) * 64 + lane];
                __builtin_amdgcn_s_setprio(1);
#pragma unroll
                for (int hr = 0; hr < 6; ++hr) {
                    bf16x4 af = *reinterpret_cast<const bf16x4*>(slu + raB[dx][hr]);
#pragma unroll
                    for (int dy = 0; dy < 3; ++dy) {
                        int y = hr - dy;
                        if (y >= 0 && y < 4) {
                            acc[y][0] = mfma16(af, bf[dy][0], acc[y][0]);
                            acc[y][1] = mfma16(af, bf[dy][1], acc[y][1]);
                        }
                    }
                }
                __builtin_amdgcn_s_setprio(0);
            }
        }
        wl += 18 * 64;
    }

    // base half 1 (ch 16-31): slu written during cc=4..7, all visible
    {
#pragma unroll
        for (int dx = 0; dx < 3; ++dx) {
            bf16x4 bf[3][2];
#pragma unroll
            for (int dy = 0; dy < 3; ++dy)
#pragma unroll
                for (int nf = 0; nf < 2; ++nf)
                    bf[dy][nf] = wfb[((((g * 2 + 1) * 3 + dx) * 3 + dy) * 2 + nf) * 64 + lane];
            __builtin_amdgcn_s_setprio(1);
#pragma unroll
            for (int hr = 0; hr < 6; ++hr) {
                bf16x4 af = *reinterpret_cast<const bf16x4*>(slu + raB[dx][hr]);
#pragma unroll
                for (int dy = 0; dy < 3; ++dy) {
                    int y = hr - dy;
                    if (y >= 0 && y < 4) {
                        acc[y][0] = mfma16(af, bf[dy][0], acc[y][0]);
                        acc[y][1] = mfma16(af, bf[dy][1], acc[y][1]);
                    }
                }
            }
            __builtin_amdgcn_s_setprio(0);
        }
    }

    // write hb (bf16): row (m) = x = lhi*4 + reg, col (n) = co = lrow
#pragma unroll
    for (int y = 0; y < 4; ++y) {
        int oy = ty + w * 4 + y;
#pragma unroll
        for (int nf = 0; nf < 2; ++nf) {
            int co = g * 32 + nf * 16 + lrow;
            uint2 o = {bfpack2_typed(acc[y][nf][0], acc[y][nf][1]),
                       bfpack2_typed(acc[y][nf][2], acc[y][nf][3])};
            *reinterpret_cast<uint2*>(
                &hb[(((size_t)b * COUT + co) * 64 + oy) * 64 + tx + lhi * 4]) = o;
        }
    }

    // fused BN partial sums (deterministic; pre-rounding accs)
    float s0 = 0.0f, q0 = 0.0f, s1 = 0.0f, q1 = 0.0f;
#pragma unroll
    for (int y = 0; y < 4; ++y)
#pragma unroll
        for (int i = 0; i < 4; ++i) {
            float a0 = acc[y][0][i], a1 = acc[y][1][i];
            s0 += a0; q0 = fmaf(a0, a0, q0);
            s1 += a1; q1 = fmaf(a1, a1, q1);
        }
    s0 += __shfl_xor(s0, 16); s0 += __shfl_xor(s0, 32);
    q0 += __shfl_xor(q0, 16); q0 += __shfl_xor(q0, 32);
    s1 += __shfl_xor(s1, 16); s1 += __shfl_xor(s1, 32);
    q1 += __shfl_xor(q1, 16); q1 += __shfl_xor(q1, 32);
    __syncthreads();
    float* stb = reinterpret_cast<float*>(lds);
    if (lane < 16) {
        int base = (w * 16 + lane) * 4;
        stb[base] = s0; stb[base + 1] = q0;
        stb[base + 2] = s1; stb[base + 3] = q1;
    }
    __syncthreads();
    if (tid < 64) {
        int slot = tid >> 1;
        int j = tid & 1;
        int lr = slot & 15, nf = slot >> 4;
        float a = 0.0f;
#pragma unroll
        for (int wv = 0; wv < 4; ++wv)
            a += stb[(wv * 16 + lr) * 4 + nf * 2 + j];
        partial2[blk * 64 + tid] = a;
    }
}

// ---- BN stats: one block per channel, reduce 256 block-partials ----
__global__ void __launch_bounds__(256) bnstat2_kernel(
    const float* __restrict__ partial2, const float* __restrict__ gamma,
    const float* __restrict__ beta, float* __restrict__ stats) {
    int co = blockIdx.x;
    int t = threadIdx.x;
    int g = co >> 5, loc = co & 31;
    int b = t >> 4, tile = t & 15;
    int blk = (b * 8 + g) * 16 + tile;
    float s = partial2[blk * 64 + loc * 2];
    float ss = partial2[blk * 64 + loc * 2 + 1];
    __shared__ float r1[256], r2[256];
    r1[t] = s; r2[t] = ss;
    __syncthreads();
    for (int o = 128; o > 0; o >>= 1) {
        if (t < o) { r1[t] += r1[t + o]; r2[t] += r2[t + o]; }
        __syncthreads();
    }
    if (t == 0) {
        const float invn = 1.0f / 65536.0f;
        float mean = r1[0] * invn;
        float var = r2[0] * invn - mean * mean;
        float sc = gamma[co] * rsqrtf(var + 1e-5f);
        stats[2 * co] = sc;
        stats[2 * co + 1] = beta[co] - mean * sc;
    }
}

// ---- BN apply: read hb (bf16, uint4 of 8), write d_out (fp32) ----
__global__ void __launch_bounds__(256) bnapply_kernel(
    const unsigned short* __restrict__ hb, const float* __restrict__ stats,
    float* __restrict__ out) {
    int i = blockIdx.x * 256 + threadIdx.x;   // 2,097,152 threads x 8 elems
    int co = (i >> 9) & 255;                  // 512 groups per (b,co) plane
    float sc = stats[2 * co], sh = stats[2 * co + 1];
    uint4 v = *reinterpret_cast<const uint4*>(hb + (size_t)i * 8);
    float4 o0, o1;
    o0.x = fmaf(__uint_as_float(v.x << 16), sc, sh);
    o0.y = fmaf(__uint_as_float(v.x & 0xFFFF0000u), sc, sh);
    o0.z = fmaf(__uint_as_float(v.y << 16), sc, sh);
    o0.w = fmaf(__uint_as_float(v.y & 0xFFFF0000u), sc, sh);
    o1.x = fmaf(__uint_as_float(v.z << 16), sc, sh);
    o1.y = fmaf(__uint_as_float(v.z & 0xFFFF0000u), sc, sh);
    o1.z = fmaf(__uint_as_float(v.w << 16), sc, sh);
    o1.w = fmaf(__uint_as_float(v.w & 0xFFFF0000u), sc, sh);
    float4* op = reinterpret_cast<float4*>(out + (size_t)i * 8);
    op[0] = o0;
    op[1] = o1;
}

extern "C" void kernel_launch(void* const* d_in, const int* in_sizes, int n_in,
                              void* d_out, int out_size, void* d_ws, size_t ws_size,
                              hipStream_t stream) {
    const float* x   = (const float*)d_in[0];
    const float* wb1 = (const float*)d_in[1];
    const float* bb1 = (const float*)d_in[2];
    const float* ws1 = (const float*)d_in[3];
    const float* wb2 = (const float*)d_in[4];
    const float* bb2 = (const float*)d_in[5];
    const float* ws2 = (const float*)d_in[6];
    const float* gamma = (const float*)d_in[7];
    const float* beta  = (const float*)d_in[8];

    char* ws = (char*)d_ws;
    unsigned short* wfs  = (unsigned short*)ws;              // 1,179,648 B
    unsigned short* wfb  = (unsigned short*)(ws + 1179648);  // 147,456 B
    unsigned short* wf1s = (unsigned short*)(ws + 1327104);  // 65,536 B
    unsigned short* wf1b = (unsigned short*)(ws + 1392640);  // 16,384 B
    float* partial2 = (float*)(ws + 1409024);                // 524,288 B
    float* stats    = (float*)(ws + 1933312);                // 2,048 B
    unsigned short* h1 = (unsigned short*)(ws + 1935360);    // 33,554,432 B
    unsigned short* hb = (unsigned short*)(ws + 35489792);   // 33,554,432 B

    repack2_kernel<<<(WFS_ELEMS + 255) / 256, 256, 0, stream>>>(
        wb1, ws1, wb2, ws2, wfs, wfb, wf1s, wf1b);
    kan1m_kernel<<<BATCH * GROUPS * 16, 256, 0, stream>>>(
        x, (const bf16x8*)wf1s, (const bf16x8*)wf1b, bb1, h1);
    kan2_mfma6_kernel<<<BATCH * GROUPS * 16, 256, 0, stream>>>(
        h1, (const bf16x8*)wfs, (const bf16x4*)wfb, bb2, hb, partial2);
    bnstat2_kernel<<<COUT, 256, 0, stream>>>(partial2, gamma, beta, stats);
    bnapply_kernel<<<8192, 256, 0, stream>>>(hb, stats, (float*)d_out);
}

// Round 25
// 148.611 us; speedup vs baseline: 3.4528x; 2.0795x over previous
//
#include <hip/hip_runtime.h>
#include <hip/hip_bf16.h>
#include <stdint.h>

// GSC_kan: two grouped KAN convs (1x1, 3x3; G=8) + BatchNorm.
// Round 25: REVERT to R22 (148.7us, best measured). R23/R24 falsified the
// occupancy-via-LDS hypothesis: even at 31KB LDS occupancy stays ~30%
// (VGPR/scheduling-bound, not LDS-bound), and the slu-halving machinery
// spills past the 84-reg budget. R22 = kan2 41.5KB LDS / 84 VGPR / no
// spill, bf16 h1+hb, fused BN partials, bf16-read bnapply.

#define NB 8
#define NF 9
#define CIN 128
#define COUT 256
#define GROUPS 8
#define HW 4096
#define BATCH 16

#define WFS_ELEMS 589824   // 256 * 32 * 8 * 9
#define WFB_ELEMS 73728    // 256 * 32 * 9
#define WF1S_ELEMS 32768
#define WF1B_ELEMS 8192

typedef __attribute__((ext_vector_type(8))) short bf16x8;
typedef __attribute__((ext_vector_type(4))) float f32x4;

__device__ __forceinline__ unsigned bf16r(float f) {
    union { float f; unsigned u; } c; c.f = f;
    unsigned r = c.u + 0x7FFF + ((c.u >> 16) & 1);   // RNE
    return r >> 16;
}
__device__ __forceinline__ unsigned bfpack2(float lo, float hi) {
    unsigned r;
    asm("v_cvt_pk_bf16_f32 %0, %1, %2" : "=v"(r) : "v"(lo), "v"(hi));
    return r;
}
// typed pack: two __float2bfloat16 (proven R18/R20) -> one u32 word
__device__ __forceinline__ unsigned bfpack2_typed(float lo, float hi) {
    __hip_bfloat16 a = __float2bfloat16(lo);
    __hip_bfloat16 b = __float2bfloat16(hi);
    unsigned short ua, ub;
    __builtin_memcpy(&ua, &a, 2);
    __builtin_memcpy(&ub, &b, 2);
    return (unsigned)ua | ((unsigned)ub << 16);
}

__device__ __forceinline__ float silu_fast(float v) {
    float e = __builtin_amdgcn_exp2f(v * -1.44269504088896f);
    return v * __builtin_amdgcn_rcpf(1.0f + e);
}

// uniform-knot cubic B-spline: 4 nonzero cardinal weights at interval k.
__device__ __forceinline__ void spline_w(float v, float& w0, float& w1,
                                         float& w2, float& w3, int& k) {
    float s = (v + 2.2f) * 2.5f;
    float fk = floorf(s);
    k = (int)fk;
    float u = s - fk;
    float um = 1.0f - u;
    float u2 = u * u, u3 = u2 * u;
    w0 = um * um * um * (1.0f / 6.0f);
    w1 = (3.0f * u3 - 6.0f * u2 + 4.0f) * (1.0f / 6.0f);
    w2 = (-3.0f * u3 + 3.0f * u2 + 3.0f * u + 1.0f) * (1.0f / 6.0f);
    w3 = u3 * (1.0f / 6.0f);
}

// ---- build the 8-bf16 spline row (zeros except w0..w3 at kk..kk+3) ----
__device__ __forceinline__ uint4 spline_row(float v, bool in, float& sv) {
    sv = silu_fast(v);
    float w0, w1, w2, w3; int k;
    spline_w(v, w0, w1, w2, w3, k);
    unsigned W0 = bfpack2(w0, w1);
    unsigned W1 = bfpack2(w2, w3);
    int kk = in ? (k - 3) : 99;                  // sentinel -> all-zero row
    unsigned odd = (unsigned)kk & 1u;
    unsigned A = W0 << 16;
    unsigned B = (W0 >> 16) | (W1 << 16);
    unsigned C = W1 >> 16;
    unsigned t0 = odd ? A : W0;
    unsigned t1 = odd ? B : W1;
    unsigned t2 = odd ? C : 0u;
    int q = kk >> 1;                             // floor((k-3)/2)
    uint4 pk;
    pk.x = (q == 0) ? t0 : (q == -1) ? t1 : (q == -2) ? t2 : 0u;
    pk.y = (q == 1) ? t0 : (q == 0)  ? t1 : (q == -1) ? t2 : 0u;
    pk.z = (q == 2) ? t0 : (q == 1)  ? t1 : (q == 0)  ? t2 : 0u;
    pk.w = (q == 3) ? t0 : (q == 2)  ? t1 : (q == 1)  ? t2 : 0u;
    return pk;
}

// expansion from raw bf16 bits (full-register int in)
__device__ __forceinline__ void expand_u(int raw, bool in,
                                         uint4& pk, unsigned& su) {
    float v = __uint_as_float(((unsigned)raw) << 16);
    float sv;
    pk = spline_row(v, in, sv);
    su = bf16r(sv);
}

// ---- repack: wfs/wfb (kan2) and wf1s/wf1b (kan1) bf16 B-fragment layouts ----
__global__ void __launch_bounds__(256) repack2_kernel(
    const float* __restrict__ wb1, const float* __restrict__ ws1,
    const float* __restrict__ wb2, const float* __restrict__ ws2,
    unsigned short* __restrict__ wfs, unsigned short* __restrict__ wfb,
    unsigned short* __restrict__ wf1s, unsigned short* __restrict__ wf1b) {
    int i = blockIdx.x * 256 + threadIdx.x;
    if (i < WF1S_ELEMS) {   // [g][cc4][nf2][lane64][j8]
        int j = i & 7;
        int lane = (i >> 3) & 63;
        int nf = (i >> 9) & 1;
        int cc = (i >> 10) & 3;
        int g = i >> 12;
        int c_loc = cc * 4 + (lane >> 4);
        int cog = g * 32 + nf * 16 + (lane & 15);
        wf1s[i] = (unsigned short)bf16r(ws1[cog * 128 + c_loc * 8 + j]);
    }
    if (i < WF1B_ELEMS) {   // [g][nf2][lane64][j8], k=(lane>>4)*8+j, zero k>=16
        int j = i & 7;
        int lane = (i >> 3) & 63;
        int nf = (i >> 9) & 1;
        int g = (i >> 10) & 7;
        int k = (lane >> 4) * 8 + j;
        int cog = g * 32 + nf * 16 + (lane & 15);
        wf1b[i] = (k < 16) ? (unsigned short)bf16r(wb1[cog * 16 + k]) : 0;
    }
    if (i < WFB_ELEMS) {    // [g][dx3][dy3][nf2][lane64][j8]
        int j = i & 7;
        int lane = (i >> 3) & 63;
        int nf = (i >> 9) & 1;
        int t = i >> 10;
        int dy = t % 3; t /= 3;
        int dx = t % 3; t /= 3;
        int g = t;
        int ch = (lane >> 4) * 8 + j;
        int cog = g * 32 + nf * 16 + (lane & 15);
        wfb[i] = (unsigned short)bf16r(wb2[((cog * 32 + ch) * 3 + dy) * 3 + dx]);
    }
    if (i < WFS_ELEMS) {    // [g][cc8][dx3][dy3][nf2][lane64][j8]
        int j = i & 7;
        int t = i >> 3;
        int lane = t & 63; t >>= 6;
        int nf = t & 1; t >>= 1;
        int dy = t % 3; t /= 3;
        int dx = t % 3; t /= 3;
        int cc = t & 7; t >>= 3;
        int g = t;
        int c_loc = cc * 4 + (lane >> 4);
        int cog = g * 32 + nf * 16 + (lane & 15);
        float v = ws2[((cog * 256 + c_loc * 8 + j) * 3 + dy) * 3 + dx];
        wfs[i] = (unsigned short)bf16r(v);
    }
}

// ---- layer 1: 1x1 grouped KAN conv via bf16 MFMA; h1 out = bf16 ----
__global__ void __launch_bounds__(256, 4) kan1m_kernel(
    const float* __restrict__ x, const bf16x8* __restrict__ wf1s,
    const bf16x8* __restrict__ wf1b, const float* __restrict__ bb1,
    unsigned short* __restrict__ h1) {
    __shared__ __align__(16) unsigned char lds[32768];
    unsigned char* spl = lds;
    unsigned char* slu = lds + 16384;

    const int tid = threadIdx.x;
    const int lane = tid & 63;
    const int w = tid >> 6;
    const int blk = blockIdx.x;
    const int tile = blk & 15;
    const int g = (blk >> 4) & 7;
    const int b = blk >> 7;
    const int lrow = lane & 15;
    const int lhi = lane >> 4;
    const int posg0 = tile * 256;

    {
        int key = (tid >> 1) & 3;
        uint4 z = {0, 0, 0, 0};
        *reinterpret_cast<uint4*>(slu + tid * 64 + ((2 ^ key) << 4)) = z;
        *reinterpret_cast<uint4*>(slu + tid * 64 + ((3 ^ key) << 4)) = z;
    }

    const float* xg = x + ((size_t)b * CIN + g * 16) * HW + posg0;

    float xreg[4];
#pragma unroll
    for (int it = 0; it < 4; ++it) xreg[it] = xg[it * HW + tid];

    f32x4 acc[4][2];
#pragma unroll
    for (int m = 0; m < 4; ++m)
#pragma unroll
        for (int nf = 0; nf < 2; ++nf) {
            float bias = bb1[g * 32 + nf * 16 + lrow];
            acc[m][nf] = (f32x4){bias, bias, bias, bias};
        }

    for (int cc = 0; cc < 4; ++cc) {
        __syncthreads();
        int key = (tid >> 1) & 3;
#pragma unroll
        for (int it = 0; it < 4; ++it) {
            float sv;
            uint4 pk = spline_row(xreg[it], true, sv);
            *reinterpret_cast<uint4*>(spl + tid * 64 + ((it ^ key) << 4)) = pk;
            int cg = cc * 4 + it;
            *reinterpret_cast<unsigned short*>(
                slu + tid * 64 + (((cg >> 3) ^ key) << 4) + (cg & 7) * 2) =
                (unsigned short)bf16r(sv);
        }
        if (cc < 3) {
#pragma unroll
            for (int it = 0; it < 4; ++it)
                xreg[it] = xg[((cc + 1) * 4 + it) * HW + tid];
        }
        __syncthreads();
        const bf16x8* wpc = wf1s + (size_t)((g * 4 + cc) * 2) * 64;
        bf16x8 bf0 = wpc[lane];
        bf16x8 bf1 = wpc[64 + lane];
#pragma unroll
        for (int m = 0; m < 4; ++m) {
            int pos = w * 64 + m * 16 + lrow;
            int ra = pos * 64 + ((lhi ^ ((pos >> 1) & 3)) << 4);
            bf16x8 af = *reinterpret_cast<const bf16x8*>(spl + ra);
            acc[m][0] = __builtin_amdgcn_mfma_f32_16x16x32_bf16(af, bf0, acc[m][0], 0, 0, 0);
            acc[m][1] = __builtin_amdgcn_mfma_f32_16x16x32_bf16(af, bf1, acc[m][1], 0, 0, 0);
        }
    }
    {
        const bf16x8* wpb = wf1b + (size_t)(g * 2) * 64;
        bf16x8 bf0 = wpb[lane];
        bf16x8 bf1 = wpb[64 + lane];
#pragma unroll
        for (int m = 0; m < 4; ++m) {
            int pos = w * 64 + m * 16 + lrow;
            int ra = pos * 64 + ((lhi ^ ((pos >> 1) & 3)) << 4);
            bf16x8 af = *reinterpret_cast<const bf16x8*>(slu + ra);
            acc[m][0] = __builtin_amdgcn_mfma_f32_16x16x32_bf16(af, bf0, acc[m][0], 0, 0, 0);
            acc[m][1] = __builtin_amdgcn_mfma_f32_16x16x32_bf16(af, bf1, acc[m][1], 0, 0, 0);
        }
    }
    // typed bf16 epilogue, packed into one uint2 (8B) store per (m,nf)
#pragma unroll
    for (int m = 0; m < 4; ++m)
#pragma unroll
        for (int nf = 0; nf < 2; ++nf) {
            int co = g * 32 + nf * 16 + lrow;
            size_t base = ((size_t)b * COUT + co) * HW + posg0 + w * 64 + m * 16 + lhi * 4;
            uint2 o = {bfpack2_typed(acc[m][nf][0], acc[m][nf][1]),
                       bfpack2_typed(acc[m][nf][2], acc[m][nf][3])};
            *reinterpret_cast<uint2*>(&h1[base]) = o;
        }
}

// ---- MFMA over one dx tap-column with precomputed LDS addrs ----
__device__ __forceinline__ void mfma_hr(
    const unsigned char* __restrict__ base, const int (&ra)[6],
    const bf16x8 (&bf)[3][2], f32x4 (&acc)[4][2]) {
#pragma unroll
    for (int hr = 0; hr < 6; ++hr) {
        bf16x8 af = *reinterpret_cast<const bf16x8*>(base + ra[hr]);
#pragma unroll
        for (int dy = 0; dy < 3; ++dy) {
            int y = hr - dy;
            if (y >= 0 && y < 4) {
                acc[y][0] = __builtin_amdgcn_mfma_f32_16x16x32_bf16(af, bf[dy][0], acc[y][0], 0, 0, 0);
                acc[y][1] = __builtin_amdgcn_mfma_f32_16x16x32_bf16(af, bf[dy][1], acc[y][1], 0, 0, 0);
            }
        }
    }
}

// ---- layer 2: 3x3 grouped KAN conv (R20 structure; bf16 hb output) ----
__global__ void __launch_bounds__(256, 3) kan2_mfma5_kernel(
    const unsigned short* __restrict__ h1, const bf16x8* __restrict__ wfs,
    const bf16x8* __restrict__ wfb, const float* __restrict__ bb2,
    unsigned short* __restrict__ hb, float* __restrict__ partial2) {
    __shared__ __align__(16) unsigned char lds[41472];
    unsigned char* spl = lds;            // 20736 B
    unsigned char* slu = lds + 20736;    // 20736 B

    const int tid = threadIdx.x;
    const int lane = tid & 63;
    const int w = tid >> 6;
    const int blk = blockIdx.x;
    const int tile = blk & 15;
    const int g = (blk >> 4) & 7;
    const int b = blk >> 7;
    const int ty = (tile >> 2) * 16, tx = (tile & 3) * 16;
    const int lrow = lane & 15;
    const int lhi = lane >> 4;

    // staging descriptors (all cc-invariant)
    int offv[6], wadS[6], sluB[6], keysh[6];
#pragma unroll
    for (int it = 0; it < 6; ++it) {
        int e = tid + it * 256;
        int ch = (e * 3237) >> 20;       // e/324 for e<1296
        int p = e - ch * 324;
        int hy = (p * 57) >> 10;         // p/18 for p<324
        int hx = p - hy * 18;
        int iy = ty + hy - 1, ix = tx + hx - 1;
        bool in = ((unsigned)iy < 64u) & ((unsigned)ix < 64u);
        offv[it] = in ? (ch * HW + iy * 64 + ix) : -1;
        int key = (p >> 1) & 3;
        wadS[it] = p * 64 + ((ch ^ key) << 4);
        sluB[it] = p * 64 + ch * 2;
        keysh[it] = key << 4;
    }

    // A-frag LDS read addrs (cc-invariant; also valid for slu base phase)
    const int pbase0 = (w * 4) * 18 + lrow;
    int raA[3][6];
#pragma unroll
    for (int dx = 0; dx < 3; ++dx)
#pragma unroll
        for (int hr = 0; hr < 6; ++hr) {
            int p = pbase0 + dx + hr * 18;
            raA[dx][hr] = p * 64 + ((lhi ^ ((p >> 1) & 3)) << 4);
        }

    const unsigned short* h1g = h1 + (size_t)(b * COUT + g * 32) * HW;

    int vregU[6];
    uint4 ereg[6];
    unsigned sreg[6];
    // prologue: load+expand chunk 0; load chunk 1
#pragma unroll
    for (int it = 0; it < 6; ++it)
        if (it < 5 || tid < 16)
            vregU[it] = (offv[it] >= 0) ? (int)h1g[offv[it]] : 0;
#pragma unroll
    for (int it = 0; it < 6; ++it)
        if (it < 5 || tid < 16)
            expand_u(vregU[it], offv[it] >= 0, ereg[it], sreg[it]);
#pragma unroll
    for (int it = 0; it < 6; ++it)
        if (it < 5 || tid < 16)
            vregU[it] = (offv[it] >= 0) ? (int)h1g[4 * HW + offv[it]] : 0;

    f32x4 acc[4][2];
#pragma unroll
    for (int y = 0; y < 4; ++y)
#pragma unroll
        for (int nf = 0; nf < 2; ++nf) {
            float bias = bb2[g * 32 + nf * 16 + lrow];
            acc[y][nf] = (f32x4){bias, bias, bias, bias};
        }

    const bf16x8* wl = wfs + (size_t)(g * 8) * 18 * 64 + lane;

    for (int cc = 0; cc < 8; ++cc) {
        // dx=0 B-frags issued before stage (in flight across barrier)
        bf16x8 bf0[3][2];
#pragma unroll
        for (int dy = 0; dy < 3; ++dy)
#pragma unroll
            for (int nf = 0; nf < 2; ++nf)
                bf0[dy][nf] = wl[(dy * 2 + nf) * 64];

        __syncthreads();                 // spl free (prev MFMA done)
        {
            int t4 = (cc >> 1) << 4;
            int u8 = (cc & 1) << 3;
#pragma unroll
            for (int it = 0; it < 6; ++it)
                if (it < 5 || tid < 16) {
                    *reinterpret_cast<uint4*>(spl + wadS[it]) = ereg[it];
                    *reinterpret_cast<unsigned short*>(
                        slu + sluB[it] + (t4 ^ keysh[it]) + u8) =
                        (unsigned short)sreg[it];
                }
        }
        __syncthreads();                 // staging complete

        bf16x8 bf1[3][2], bf2[3][2];
#pragma unroll
        for (int dy = 0; dy < 3; ++dy)
#pragma unroll
            for (int nf = 0; nf < 2; ++nf)
                bf1[dy][nf] = wl[(6 + dy * 2 + nf) * 64];
        __builtin_amdgcn_s_setprio(1);
        mfma_hr(spl, raA[0], bf0, acc);
        __builtin_amdgcn_s_setprio(0);
#pragma unroll
        for (int dy = 0; dy < 3; ++dy)
#pragma unroll
            for (int nf = 0; nf < 2; ++nf)
                bf2[dy][nf] = wl[(12 + dy * 2 + nf) * 64];
        __builtin_amdgcn_s_setprio(1);
        mfma_hr(spl, raA[1], bf1, acc);
        __builtin_amdgcn_s_setprio(0);
        // expansion for cc+1 + loads for cc+2 (overlap MFMA pipe)
        if (cc < 7) {
#pragma unroll
            for (int it = 0; it < 6; ++it)
                if (it < 5 || tid < 16)
                    expand_u(vregU[it], offv[it] >= 0, ereg[it], sreg[it]);
        }
        if (cc < 6) {
#pragma unroll
            for (int it = 0; it < 6; ++it)
                if (it < 5 || tid < 16)
                    vregU[it] = (offv[it] >= 0)
                        ? (int)h1g[(size_t)((cc + 2) * 4) * HW + offv[it]] : 0;
        }
        __builtin_amdgcn_s_setprio(1);
        mfma_hr(spl, raA[2], bf2, acc);
        __builtin_amdgcn_s_setprio(0);
        wl += 18 * 64;
    }

    // base branch: silu plane, K = 32 channels (reuses raA on slu)
    {
        const bf16x8* wlb = wfb + (size_t)(g * 3) * 6 * 64 + lane;
#pragma unroll
        for (int dx = 0; dx < 3; ++dx) {
            bf16x8 bf[3][2];
#pragma unroll
            for (int dy = 0; dy < 3; ++dy)
#pragma unroll
                for (int nf = 0; nf < 2; ++nf)
                    bf[dy][nf] = wlb[(dx * 6 + dy * 2 + nf) * 64];
            __builtin_amdgcn_s_setprio(1);
            mfma_hr(slu, raA[dx], bf, acc);
            __builtin_amdgcn_s_setprio(0);
        }
    }

    // write hb (bf16): row (m) = x = lhi*4 + reg, col (n) = co = lrow
#pragma unroll
    for (int y = 0; y < 4; ++y) {
        int oy = ty + w * 4 + y;
#pragma unroll
        for (int nf = 0; nf < 2; ++nf) {
            int co = g * 32 + nf * 16 + lrow;
            uint2 o = {bfpack2_typed(acc[y][nf][0], acc[y][nf][1]),
                       bfpack2_typed(acc[y][nf][2], acc[y][nf][3])};
            *reinterpret_cast<uint2*>(
                &hb[(((size_t)b * COUT + co) * 64 + oy) * 64 + tx + lhi * 4]) = o;
        }
    }

    // fused BN partial sums (deterministic; pre-rounding accs)
    float s0 = 0.0f, q0 = 0.0f, s1 = 0.0f, q1 = 0.0f;
#pragma unroll
    for (int y = 0; y < 4; ++y)
#pragma unroll
        for (int i = 0; i < 4; ++i) {
            float a0 = acc[y][0][i], a1 = acc[y][1][i];
            s0 += a0; q0 = fmaf(a0, a0, q0);
            s1 += a1; q1 = fmaf(a1, a1, q1);
        }
    s0 += __shfl_xor(s0, 16); s0 += __shfl_xor(s0, 32);
    q0 += __shfl_xor(q0, 16); q0 += __shfl_xor(q0, 32);
    s1 += __shfl_xor(s1, 16); s1 += __shfl_xor(s1, 32);
    q1 += __shfl_xor(q1, 16); q1 += __shfl_xor(q1, 32);
    __syncthreads();
    float* stb = reinterpret_cast<float*>(lds);
    if (lane < 16) {
        int base = (w * 16 + lane) * 4;
        stb[base] = s0; stb[base + 1] = q0;
        stb[base + 2] = s1; stb[base + 3] = q1;
    }
    __syncthreads();
    if (tid < 64) {
        int slot = tid >> 1;
        int j = tid & 1;
        int lr = slot & 15, nf = slot >> 4;
        float a = 0.0f;
#pragma unroll
        for (int wv = 0; wv < 4; ++wv)
            a += stb[(wv * 16 + lr) * 4 + nf * 2 + j];
        partial2[blk * 64 + tid] = a;
    }
}

// ---- BN stats: one block per channel, reduce 256 block-partials ----
__global__ void __launch_bounds__(256) bnstat2_kernel(
    const float* __restrict__ partial2, const float* __restrict__ gamma,
    const float* __restrict__ beta, float* __restrict__ stats) {
    int co = blockIdx.x;
    int t = threadIdx.x;
    int g = co >> 5, loc = co & 31;
    int b = t >> 4, tile = t & 15;
    int blk = (b * 8 + g) * 16 + tile;
    float s = partial2[blk * 64 + loc * 2];
    float ss = partial2[blk * 64 + loc * 2 + 1];
    __shared__ float r1[256], r2[256];
    r1[t] = s; r2[t] = ss;
    __syncthreads();
    for (int o = 128; o > 0; o >>= 1) {
        if (t < o) { r1[t] += r1[t + o]; r2[t] += r2[t + o]; }
        __syncthreads();
    }
    if (t == 0) {
        const float invn = 1.0f / 65536.0f;
        float mean = r1[0] * invn;
        float var = r2[0] * invn - mean * mean;
        float sc = gamma[co] * rsqrtf(var + 1e-5f);
        stats[2 * co] = sc;
        stats[2 * co + 1] = beta[co] - mean * sc;
    }
}

// ---- BN apply: read hb (bf16, uint4 of 8), write d_out (fp32) ----
__global__ void __launch_bounds__(256) bnapply_kernel(
    const unsigned short* __restrict__ hb, const float* __restrict__ stats,
    float* __restrict__ out) {
    int i = blockIdx.x * 256 + threadIdx.x;   // 2,097,152 threads x 8 elems
    int co = (i >> 9) & 255;                  // 512 groups per (b,co) plane
    float sc = stats[2 * co], sh = stats[2 * co + 1];
    uint4 v = *reinterpret_cast<const uint4*>(hb + (size_t)i * 8);
    float4 o0, o1;
    o0.x = fmaf(__uint_as_float(v.x << 16), sc, sh);
    o0.y = fmaf(__uint_as_float(v.x & 0xFFFF0000u), sc, sh);
    o0.z = fmaf(__uint_as_float(v.y << 16), sc, sh);
    o0.w = fmaf(__uint_as_float(v.y & 0xFFFF0000u), sc, sh);
    o1.x = fmaf(__uint_as_float(v.z << 16), sc, sh);
    o1.y = fmaf(__uint_as_float(v.z & 0xFFFF0000u), sc, sh);
    o1.z = fmaf(__uint_as_float(v.w << 16), sc, sh);
    o1.w = fmaf(__uint_as_float(v.w & 0xFFFF0000u), sc, sh);
    float4* op = reinterpret_cast<float4*>(out + (size_t)i * 8);
    op[0] = o0;
    op[1] = o1;
}

extern "C" void kernel_launch(void* const* d_in, const int* in_sizes, int n_in,
                              void* d_out, int out_size, void* d_ws, size_t ws_size,
                              hipStream_t stream) {
    const float* x   = (const float*)d_in[0];
    const float* wb1 = (const float*)d_in[1];
    const float* bb1 = (const float*)d_in[2];
    const float* ws1 = (const float*)d_in[3];
    const float* wb2 = (const float*)d_in[4];
    const float* bb2 = (const float*)d_in[5];
    const float* ws2 = (const float*)d_in[6];
    const float* gamma = (const float*)d_in[7];
    const float* beta  = (const float*)d_in[8];

    char* ws = (char*)d_ws;
    unsigned short* wfs  = (unsigned short*)ws;              // 1,179,648 B
    unsigned short* wfb  = (unsigned short*)(ws + 1179648);  // 147,456 B
    unsigned short* wf1s = (unsigned short*)(ws + 1327104);  // 65,536 B
    unsigned short* wf1b = (unsigned short*)(ws + 1392640);  // 16,384 B
    float* partial2 = (float*)(ws + 1409024);                // 524,288 B
    float* stats    = (float*)(ws + 1933312);                // 2,048 B
    unsigned short* h1 = (unsigned short*)(ws + 1935360);    // 33,554,432 B
    unsigned short* hb = (unsigned short*)(ws + 35489792);   // 33,554,432 B

    repack2_kernel<<<(WFS_ELEMS + 255) / 256, 256, 0, stream>>>(
        wb1, ws1, wb2, ws2, wfs, wfb, wf1s, wf1b);
    kan1m_kernel<<<BATCH * GROUPS * 16, 256, 0, stream>>>(
        x, (const bf16x8*)wf1s, (const bf16x8*)wf1b, bb1, h1);
    kan2_mfma5_kernel<<<BATCH * GROUPS * 16, 256, 0, stream>>>(
        h1, (const bf16x8*)wfs, (const bf16x8*)wfb, bb2, hb, partial2);
    bnstat2_kernel<<<COUT, 256, 0, stream>>>(partial2, gamma, beta, stats);
    bnapply_kernel<<<8192, 256, 0, stream>>>(hb, stats, (float*)d_out);
}